// Round 12
// baseline (144.423 us; speedup 1.0000x reference)
//
#include <hip/hip_runtime.h>
#include <hip/hip_bf16.h>

typedef float f32x4 __attribute__((ext_vector_type(4)));
typedef short s16x8 __attribute__((ext_vector_type(8)));

#define D_DIM 4096
#define NT 24            // 16-wide col tiles (global)
// ws byte offsets
#define SINW_OFF 3145728u                 // sinws[8][8192] f32 = 256 KiB
#define PART_OFF 3407872u                 // part[4][8192][384] f16 = 24 MiB
#define XBF_OFF  28573696u                // Xbf half-panel bf16 = 32 MiB (reused)

__device__ __forceinline__ unsigned short f2bf(float f) {
    unsigned u = __float_as_uint(f);
    u += 0x7fffu + ((u >> 16) & 1u);   // RNE
    return (unsigned short)(u >> 16);
}

__device__ __forceinline__ void gload16(const void* g, void* l) {
    __builtin_amdgcn_global_load_lds(
        (const __attribute__((address_space(1))) unsigned int*)g,
        (__attribute__((address_space(3))) unsigned int*)l, 16, 0, 0);
}

__global__ __launch_bounds__(64) void reg_init_kernel(const float* __restrict__ C,
                                                      const float* __restrict__ Csin,
                                                      float* __restrict__ reg_out) {
    if (threadIdx.x == 0)
        reg_out[0] = 0.05f * (fabsf(C[0]) + fabsf(C[1]) + fabsf(C[2]) + fabsf(Csin[0]));
}

// Build W [4096 x 384] bf16, MFMA B-fragment-packed, slab-contiguous:
// chunk = (k>>5)*NT + (n>>4); lane = ((k&31)>>3)*16 | (n&15); j = k&7.
// Slab s (32 k's) = bytes [s*24576, (s+1)*24576), 24 chunks of 1 KB.
__global__ __launch_bounds__(64) void build_w_kernel(const float* __restrict__ U1,
                                                     const float* __restrict__ U2,
                                                     const float* __restrict__ U3,
                                                     unsigned short* __restrict__ W,
                                                     float* __restrict__ reg_out) {
    const int ks = blockIdx.x / NT;
    const int ct = blockIdx.x % NT;
    const int l  = threadIdx.x;
    const int n  = ct * 16 + (l & 15);
    const int kb = ks * 32 + ((l >> 4) << 3);

    const float* src;
    float scale;
    if (n < 64)       { src = U1 + n;                  scale = 0.01f / 262144.f; }
    else if (n < 128) { src = U2 + (n - 64);           scale = 0.01f / 524288.f; }
    else if (n < 192) { src = U2 + 262144 + (n - 128); scale = 0.01f / 524288.f; }
    else if (n < 256) { src = U3 + (n - 192);          scale = 0.01f / 786432.f; }
    else if (n < 320) { src = U3 + 262144 + (n - 256); scale = 0.01f / 786432.f; }
    else              { src = U3 + 524288 + (n - 320); scale = 0.01f / 786432.f; }

    unsigned short h[8];
    float sabs = 0.f;
#pragma unroll
    for (int j = 0; j < 8; ++j) {
        float u = src[(size_t)(kb + j) * 64];
        sabs += fabsf(u);
        h[j] = f2bf(u);
    }
    uint4 pk;
    pk.x = (unsigned)h[0] | ((unsigned)h[1] << 16);
    pk.y = (unsigned)h[2] | ((unsigned)h[3] << 16);
    pk.z = (unsigned)h[4] | ((unsigned)h[5] << 16);
    pk.w = (unsigned)h[6] | ((unsigned)h[7] << 16);
    *(uint4*)(W + ((size_t)blockIdx.x * 64 + l) * 8) = pk;

    sabs *= scale;
#pragma unroll
    for (int off = 32; off >= 1; off >>= 1)
        sabs += __shfl_xor(sabs, off, 64);
    if (l == 0) atomicAdd(reg_out, sabs);
}

// Pass 1: pure barrier-free stream. grid 256 = rb(64) x ks(4); 512 thr.
// Block: 128 rows x 512 k of the kh-half. Reads X f32 (32B/thread/slab),
// computes sin, packs bf16 into frag-layout chunks:
// chunk (rb*64+k32)*8+rowfrag; lane = ((k&31)>>3)*16 | (row&15); j = k&7.
__global__ __launch_bounds__(512) void pack_kernel(const float* __restrict__ X,
                                                   unsigned short* __restrict__ Xbf,
                                                   float* __restrict__ sinws,
                                                   int kh) {
    const int t    = threadIdx.x;
    const int rb   = blockIdx.x >> 2;
    const int ks   = blockIdx.x & 3;
    const int row  = t >> 2;              // 0..127
    const int q    = t & 3;               // k-octet within 32
    const int row0 = rb * 128;

    const float* xp = X + (size_t)(row0 + row) * D_DIM + kh * 2048 + ks * 512 + q * 8;
    const int lane_o = (q << 4) | (row & 15);
    const int rf     = row >> 4;

    float sinacc = 0.f;
#pragma unroll 4
    for (int s = 0; s < 16; ++s) {
        f32x4 a = *(const f32x4*)(xp + s * 32);
        f32x4 b = *(const f32x4*)(xp + s * 32 + 4);
        sinacc += __sinf(a.x) + __sinf(a.y) + __sinf(a.z) + __sinf(a.w)
                + __sinf(b.x) + __sinf(b.y) + __sinf(b.z) + __sinf(b.w);
        uint4 pk;
        pk.x = (unsigned)f2bf(a.x) | ((unsigned)f2bf(a.y) << 16);
        pk.y = (unsigned)f2bf(a.z) | ((unsigned)f2bf(a.w) << 16);
        pk.z = (unsigned)f2bf(b.x) | ((unsigned)f2bf(b.y) << 16);
        pk.w = (unsigned)f2bf(b.z) | ((unsigned)f2bf(b.w) << 16);
        const size_t chunk = (size_t)(rb * 64 + ks * 16 + s) * 8 + rf;
        *(uint4*)(Xbf + chunk * 512 + lane_o * 8) = pk;
    }
    sinacc += __shfl_xor(sinacc, 1);
    sinacc += __shfl_xor(sinacc, 2);
    if (q == 0)
        sinws[(size_t)(kh * 4 + ks) * 8192 + row0 + row] = sinacc;
}

// Pass 2: minimal MFMA loop, zero VALU work. grid 512 = rb(64) x cs(4) x kq(2);
// 512 thr = 8 waves (4 rg x 2 cg). Block: 128 rows x 96 cols x 1024 K,
// 32 bodies BK=32. Per body: 14 gload_lds chunks (A 8 + B 6) split across
// waves (0-5: 2 chunks, 6-7: 1), triple-buffered LDS; ds_read 2 A + 3 B
// frags (lane-linear, conflict-free); lgkm wall; 6 MFMA; per-wave counted
// vmcnt (2 or 1 — NEVER 0); raw s_barrier. 2 blocks/CU.
__global__ __launch_bounds__(512, 4) void gemm_kernel(const unsigned short* __restrict__ Xbf,
                                                      const unsigned short* __restrict__ W,
                                                      _Float16* __restrict__ part,
                                                      int kh) {
    __shared__ __align__(16) char pool[43008];   // A[3][8192] @0, B[3][6144] @24576
    const int BOFF2 = 24576;

    const int t    = threadIdx.x;
    const int lane = t & 63;
    const int wv   = t >> 6;          // 0..7
    const int rg   = wv >> 1;         // 0..3
    const int cg   = wv & 1;          // 0..1
    const int bid  = blockIdx.x;
    const int rb   = bid >> 3;
    const int cs   = (bid >> 1) & 3;
    const int kq   = bid & 1;
    const int row0 = rb * 128;
    const int khk  = kh * 64 + kq * 32;   // first k32 slab index (global)
    const int kqb  = kq * 32;             // first k32 within half (Xbf index)

#define ISSUE(dd_, bufi_)                                                       \
    {                                                                           \
        int dc_ = (dd_) > 31 ? 31 : (dd_);                                      \
        if (wv < 4) {                                                           \
            const unsigned short* ga_ = Xbf                                     \
                + ((size_t)((rb * 64 + kqb + dc_) * 8 + 2 * wv)) * 512          \
                + lane * 8;                                                     \
            gload16(ga_, pool + (bufi_) * 8192 + 2 * wv * 1024);                \
            gload16(ga_ + 512, pool + (bufi_) * 8192 + (2 * wv + 1) * 1024);    \
        } else {                                                                \
            const int c0_ = (wv == 4) ? 0 : (wv == 5) ? 2 : (wv == 6) ? 4 : 5;  \
            const unsigned short* gb_ = W                                       \
                + ((size_t)(khk + dc_) * 24 + cs * 6 + c0_) * 512 + lane * 8;   \
            gload16(gb_, pool + BOFF2 + (bufi_) * 6144 + c0_ * 1024);           \
            if (wv < 6)                                                         \
                gload16(gb_ + 512, pool + BOFF2 + (bufi_) * 6144 + (c0_ + 1) * 1024); \
        }                                                                       \
    }

    f32x4 acc[2][3];
#pragma unroll
    for (int r = 0; r < 2; ++r)
#pragma unroll
        for (int c = 0; c < 3; ++c) acc[r][c] = (f32x4){0.f, 0.f, 0.f, 0.f};

    // ---- prologue: bodies 0,1 in flight; wait body 0 only ----
    ISSUE(0, 0);
    ISSUE(1, 1);
    if (wv < 6) { asm volatile("s_waitcnt vmcnt(2)" ::: "memory"); }
    else        { asm volatile("s_waitcnt vmcnt(1)" ::: "memory"); }
    __builtin_amdgcn_s_barrier();
    __builtin_amdgcn_sched_barrier(0);

#define BODY(d_, CUR, ISS)                                                      \
    {                                                                           \
        ISSUE((d_) + 2, ISS);                                                   \
        const char* ab_ = pool + (CUR) * 8192 + rg * 2048;                      \
        const char* bb_ = pool + BOFF2 + (CUR) * 6144 + cg * 3072;              \
        s16x8 a0_ = *(const s16x8*)(ab_ + lane * 16);                           \
        s16x8 a1_ = *(const s16x8*)(ab_ + 1024 + lane * 16);                    \
        s16x8 b0_ = *(const s16x8*)(bb_ + lane * 16);                           \
        s16x8 b1_ = *(const s16x8*)(bb_ + 1024 + lane * 16);                    \
        s16x8 b2_ = *(const s16x8*)(bb_ + 2048 + lane * 16);                    \
        asm volatile("s_waitcnt lgkmcnt(0)" ::: "memory");                      \
        __builtin_amdgcn_sched_barrier(0);                                      \
        __builtin_amdgcn_s_setprio(1);                                          \
        acc[0][0] = __builtin_amdgcn_mfma_f32_16x16x32_bf16(a0_, b0_, acc[0][0], 0, 0, 0); \
        acc[0][1] = __builtin_amdgcn_mfma_f32_16x16x32_bf16(a0_, b1_, acc[0][1], 0, 0, 0); \
        acc[0][2] = __builtin_amdgcn_mfma_f32_16x16x32_bf16(a0_, b2_, acc[0][2], 0, 0, 0); \
        acc[1][0] = __builtin_amdgcn_mfma_f32_16x16x32_bf16(a1_, b0_, acc[1][0], 0, 0, 0); \
        acc[1][1] = __builtin_amdgcn_mfma_f32_16x16x32_bf16(a1_, b1_, acc[1][1], 0, 0, 0); \
        acc[1][2] = __builtin_amdgcn_mfma_f32_16x16x32_bf16(a1_, b2_, acc[1][2], 0, 0, 0); \
        __builtin_amdgcn_s_setprio(0);                                          \
        if (wv < 6) { asm volatile("s_waitcnt vmcnt(2)" ::: "memory"); }        \
        else        { asm volatile("s_waitcnt vmcnt(1)" ::: "memory"); }        \
        __builtin_amdgcn_s_barrier();                                           \
        __builtin_amdgcn_sched_barrier(0);                                      \
    }

    for (int d = 0; d < 30; d += 3) {
        BODY(d,     0, 2);
        BODY(d + 1, 1, 0);
        BODY(d + 2, 2, 1);
    }
    BODY(30, 0, 2);
    BODY(31, 1, 0);
#undef BODY
#undef ISSUE

    // ---- epilogue: f16 partial write ----
    _Float16* pb = part + (size_t)(kh * 2 + kq) * 8192 * 384;
    const int lr4 = (lane >> 4) << 2;
    const int lc  = lane & 15;
#pragma unroll
    for (int rf = 0; rf < 2; ++rf)
#pragma unroll
        for (int c = 0; c < 3; ++c) {
            const int col = cs * 96 + (cg * 3 + c) * 16 + lc;
#pragma unroll
            for (int i = 0; i < 4; ++i) {
                const int rl = rg * 32 + rf * 16 + lr4 + i;
                pb[(size_t)(row0 + rl) * 384 + col] = (_Float16)acc[rf][c][i];
            }
        }
}

// combine: sum 4 K-quarter partials + 8 sin partials; nonlinear epilogue.
__global__ __launch_bounds__(512) void combine_kernel(const _Float16* __restrict__ part,
                                                      const float* __restrict__ sinws,
                                                      const float* __restrict__ C,
                                                      const float* __restrict__ beta,
                                                      const float* __restrict__ Csin,
                                                      float* __restrict__ out) {
    const int t   = threadIdx.x;
    const int row = blockIdx.x * 32 + (t >> 4);
    const int cc  = t & 15;
    const size_t rbase = (size_t)row * 384;

    float t1 = 0.f, t2 = 0.f, t3 = 0.f;
#pragma unroll
    for (int j = 0; j < 4; ++j) {
        const int c = j * 16 + cc;
        float a1 = 0.f, a2 = 0.f, b2 = 0.f, a3 = 0.f, b3 = 0.f, c3 = 0.f;
#pragma unroll
        for (int qq = 0; qq < 4; ++qq) {
            const _Float16* p = part + (size_t)qq * 8192 * 384 + rbase;
            a1 += (float)p[c];
            a2 += (float)p[64 + c];
            b2 += (float)p[128 + c];
            a3 += (float)p[192 + c];
            b3 += (float)p[256 + c];
            c3 += (float)p[320 + c];
        }
        t1 += a1;
        t2 += a2 * b2;
        t3 += a3 * b3 * c3;
    }
#pragma unroll
    for (int off = 1; off < 16; off <<= 1) {
        t1 += __shfl_xor(t1, off, 16);
        t2 += __shfl_xor(t2, off, 16);
        t3 += __shfl_xor(t3, off, 16);
    }
    if (cc == 0) {
        float s = 0.f;
#pragma unroll
        for (int v = 0; v < 8; ++v)
            s += sinws[(size_t)v * 8192 + row];
        out[row] = beta[0] + C[0] * t1 + C[1] * t2 + C[2] * t3 + Csin[0] * s;
    }
}

extern "C" void kernel_launch(void* const* d_in, const int* in_sizes, int n_in,
                              void* d_out, int out_size, void* d_ws, size_t ws_size,
                              hipStream_t stream) {
    const float* X   = (const float*)d_in[0];
    const float* U1  = (const float*)d_in[1];
    const float* U2  = (const float*)d_in[2];
    const float* U3  = (const float*)d_in[3];
    const float* Cc  = (const float*)d_in[4];
    const float* bet = (const float*)d_in[5];
    const float* Cs  = (const float*)d_in[6];
    float* out = (float*)d_out;

    unsigned short* W   = (unsigned short*)d_ws;                  // 3 MiB, frag-packed
    float* sinws        = (float*)((char*)d_ws + SINW_OFF);       // 256 KiB
    _Float16* part      = (_Float16*)((char*)d_ws + PART_OFF);    // 24 MiB
    unsigned short* Xbf = (unsigned short*)((char*)d_ws + XBF_OFF); // 32 MiB (reused per half)

    reg_init_kernel<<<1, 64, 0, stream>>>(Cc, Cs, out + 8192);
    build_w_kernel<<<128 * NT, 64, 0, stream>>>(U1, U2, U3, W, out + 8192);
    pack_kernel<<<256, 512, 0, stream>>>(X, Xbf, sinws, 0);
    gemm_kernel<<<512, 512, 0, stream>>>(Xbf, W, part, 0);
    pack_kernel<<<256, 512, 0, stream>>>(X, Xbf, sinws, 1);
    gemm_kernel<<<512, 512, 0, stream>>>(Xbf, W, part, 1);
    combine_kernel<<<256, 512, 0, stream>>>(part, sinws, Cc, bet, Cs, out);
}

// Round 13
// 105.132 us; speedup vs baseline: 1.3737x; 1.3737x over previous
//
#include <hip/hip_runtime.h>
#include <hip/hip_bf16.h>

typedef float f32x4 __attribute__((ext_vector_type(4)));
typedef short s16x8 __attribute__((ext_vector_type(8)));

#define D_DIM 4096
#define NT 24            // 16-wide col tiles (global)
#define BM 64            // rows per block
#define NBODY 16         // bodies per block, BK=64 (K per block = 1024)
// LDS: B[2 kslab][12 tiles][1024] @ 0 (24 KB), A[8 chunks][1024] @ 24576 (8 KB)
#define AOFF 24576
// ws byte offsets
#define SINW_OFF 3145728u                 // sinws[4][8192] f32 = 128 KiB
#define PART_OFF 3276800u                 // part[4][8192][384] f16 = 24 MiB

__device__ __forceinline__ unsigned short f2bf(float f) {
    unsigned u = __float_as_uint(f);
    u += 0x7fffu + ((u >> 16) & 1u);   // RNE
    return (unsigned short)(u >> 16);
}

__device__ __forceinline__ void gload16(const void* g, void* l) {
    __builtin_amdgcn_global_load_lds(
        (const __attribute__((address_space(1))) unsigned int*)g,
        (__attribute__((address_space(3))) unsigned int*)l, 16, 0, 0);
}

__global__ __launch_bounds__(64) void reg_init_kernel(const float* __restrict__ C,
                                                      const float* __restrict__ Csin,
                                                      float* __restrict__ reg_out) {
    if (threadIdx.x == 0)
        reg_out[0] = 0.05f * (fabsf(C[0]) + fabsf(C[1]) + fabsf(C[2]) + fabsf(Csin[0]));
}

// Build W [4096 x 384] bf16, MFMA B-fragment-packed, slab-contiguous:
// chunk = (k>>5)*NT + (n>>4); lane = ((k&31)>>3)*16 | (n&15); j = k&7.
__global__ __launch_bounds__(64) void build_w_kernel(const float* __restrict__ U1,
                                                     const float* __restrict__ U2,
                                                     const float* __restrict__ U3,
                                                     unsigned short* __restrict__ W,
                                                     float* __restrict__ reg_out) {
    const int ks = blockIdx.x / NT;
    const int ct = blockIdx.x % NT;
    const int l  = threadIdx.x;
    const int n  = ct * 16 + (l & 15);
    const int kb = ks * 32 + ((l >> 4) << 3);

    const float* src;
    float scale;
    if (n < 64)       { src = U1 + n;                  scale = 0.01f / 262144.f; }
    else if (n < 128) { src = U2 + (n - 64);           scale = 0.01f / 524288.f; }
    else if (n < 192) { src = U2 + 262144 + (n - 128); scale = 0.01f / 524288.f; }
    else if (n < 256) { src = U3 + (n - 192);          scale = 0.01f / 786432.f; }
    else if (n < 320) { src = U3 + 262144 + (n - 256); scale = 0.01f / 786432.f; }
    else              { src = U3 + 524288 + (n - 320); scale = 0.01f / 786432.f; }

    unsigned short h[8];
    float sabs = 0.f;
#pragma unroll
    for (int j = 0; j < 8; ++j) {
        float u = src[(size_t)(kb + j) * 64];
        sabs += fabsf(u);
        h[j] = f2bf(u);
    }
    uint4 pk;
    pk.x = (unsigned)h[0] | ((unsigned)h[1] << 16);
    pk.y = (unsigned)h[2] | ((unsigned)h[3] << 16);
    pk.z = (unsigned)h[4] | ((unsigned)h[5] << 16);
    pk.w = (unsigned)h[6] | ((unsigned)h[7] << 16);
    *(uint4*)(W + ((size_t)blockIdx.x * 64 + l) * 8) = pk;

    sabs *= scale;
#pragma unroll
    for (int off = 32; off >= 1; off >>= 1)
        sabs += __shfl_xor(sabs, off, 64);
    if (l == 0) atomicAdd(reg_out, sabs);
}

// m97-clone: grid 1024 = rb(128) x cs(2) x ks(4); 256 thr = 4 waves.
// blockIdx = rb*8 + cs*4 + ks -> XCD = (cs,ks): per-XCD W slice 384 KB.
// Block: 64 rows x 192 cols x 1024 K, 16 bodies of BK=64. ~3 blocks/CU
// co-resident (launch_bounds(256,3), 32 KB LDS) -- independent barrier
// groups cover each other's barrier drains (m114/m97 mechanism).
// Per body: each wave gload_lds's the 6 B-chunks IT consumes (wave-uniform
// dest); A staged in-reg (4 f32x4 X + sin(cs==0) + cvt + 2 ds_write_b128);
// plain __syncthreads; ds_read 8A+6B frags; 24 MFMA; __syncthreads.
__global__ __launch_bounds__(256, 3) void poly_main_kernel(const float* __restrict__ X,
                                                           const unsigned short* __restrict__ W,
                                                           _Float16* __restrict__ part,
                                                           float* __restrict__ sinws) {
    __shared__ __align__(16) char pool[32768];

    const int t    = threadIdx.x;
    const int lane = t & 63;
    const int wv   = t >> 6;          // 0..3 (also the wave's col-group)
    const int bid  = blockIdx.x;
    const int rb   = bid >> 3;
    const int cs   = (bid >> 2) & 1;
    const int ks   = bid & 3;
    const int row0 = rb * BM;
    const bool doSin = (cs == 0);

    // A staging: thread -> (row sr, k-octet q) in both 32-k slabs of the body
    const int sr = t >> 2;            // 0..63
    const int q  = t & 3;             // k-octet within 32
    const float* xp = X + (size_t)(row0 + sr) * D_DIM + ks * 1024 + q * 8;
    const int aw0 = AOFF + (sr >> 4) * 1024 + (((q << 4) | (sr & 15)) << 4);
    const int aw1 = aw0 + 4096;       // kslab 1 (chunks 4..7)

    f32x4 acc[4][3];
#pragma unroll
    for (int r = 0; r < 4; ++r)
#pragma unroll
        for (int c = 0; c < 3; ++c) acc[r][c] = (f32x4){0.f, 0.f, 0.f, 0.f};
    float sinacc = 0.f;

    for (int d = 0; d < NBODY; ++d) {
        // ---- issue B: wave wv loads its own 6 chunks (2 kslabs x 3 tiles) ----
        const size_t slabg = (size_t)(ks * 32 + 2 * d);
#pragma unroll
        for (int ksl = 0; ksl < 2; ++ksl)
#pragma unroll
            for (int j = 0; j < 3; ++j) {
                const unsigned short* g = W
                    + ((slabg + ksl) * 24 + cs * 12 + wv * 3 + j) * 512 + lane * 8;
                gload16(g, pool + ksl * 12288 + (wv * 3 + j) * 1024);
            }
        // ---- stage A: 2 kslabs x 8 elems per thread ----
#pragma unroll
        for (int ksl = 0; ksl < 2; ++ksl) {
            f32x4 a = *(const f32x4*)(xp + d * 64 + ksl * 32);
            f32x4 b = *(const f32x4*)(xp + d * 64 + ksl * 32 + 4);
            if (doSin)
                sinacc += __sinf(a.x) + __sinf(a.y) + __sinf(a.z) + __sinf(a.w)
                        + __sinf(b.x) + __sinf(b.y) + __sinf(b.z) + __sinf(b.w);
            uint4 pk;
            pk.x = (unsigned)f2bf(a.x) | ((unsigned)f2bf(a.y) << 16);
            pk.y = (unsigned)f2bf(a.z) | ((unsigned)f2bf(a.w) << 16);
            pk.z = (unsigned)f2bf(b.x) | ((unsigned)f2bf(b.y) << 16);
            pk.w = (unsigned)f2bf(b.z) | ((unsigned)f2bf(b.w) << 16);
            *(uint4*)(pool + (ksl ? aw1 : aw0)) = pk;
        }
        __syncthreads();   // drains gload_lds (vmcnt) + ds_writes (lgkm)

        // ---- compute: 8 A-frags + 6 B-frags, 24 MFMA ----
#pragma unroll
        for (int ksl = 0; ksl < 2; ++ksl) {
            s16x8 b0 = *(const s16x8*)(pool + ksl * 12288 + (wv * 3 + 0) * 1024 + lane * 16);
            s16x8 b1 = *(const s16x8*)(pool + ksl * 12288 + (wv * 3 + 1) * 1024 + lane * 16);
            s16x8 b2 = *(const s16x8*)(pool + ksl * 12288 + (wv * 3 + 2) * 1024 + lane * 16);
#pragma unroll
            for (int rf = 0; rf < 4; ++rf) {
                s16x8 af = *(const s16x8*)(pool + AOFF + (ksl * 4 + rf) * 1024 + lane * 16);
                acc[rf][0] = __builtin_amdgcn_mfma_f32_16x16x32_bf16(af, b0, acc[rf][0], 0, 0, 0);
                acc[rf][1] = __builtin_amdgcn_mfma_f32_16x16x32_bf16(af, b1, acc[rf][1], 0, 0, 0);
                acc[rf][2] = __builtin_amdgcn_mfma_f32_16x16x32_bf16(af, b2, acc[rf][2], 0, 0, 0);
            }
        }
        __syncthreads();   // LDS reads done before next body's overwrite
    }

    // ---- epilogue: f16 partial write + sin partial ----
    _Float16* pb = part + (size_t)ks * 8192 * 384;
    const int lr4 = (lane >> 4) << 2;
    const int lc  = lane & 15;
#pragma unroll
    for (int rf = 0; rf < 4; ++rf)
#pragma unroll
        for (int c = 0; c < 3; ++c) {
            const int col = cs * 192 + (wv * 3 + c) * 16 + lc;
#pragma unroll
            for (int i = 0; i < 4; ++i)
                pb[(size_t)(row0 + rf * 16 + lr4 + i) * 384 + col] = (_Float16)acc[rf][c][i];
        }

    if (doSin) {
        sinacc += __shfl_xor(sinacc, 1);
        sinacc += __shfl_xor(sinacc, 2);
        if (q == 0)
            sinws[(size_t)ks * 8192 + row0 + sr] = sinacc;
    }
}

// combine: sum 4 K-quarter partials + 4 sin partials; nonlinear epilogue.
__global__ __launch_bounds__(512) void combine_kernel(const _Float16* __restrict__ part,
                                                      const float* __restrict__ sinws,
                                                      const float* __restrict__ C,
                                                      const float* __restrict__ beta,
                                                      const float* __restrict__ Csin,
                                                      float* __restrict__ out) {
    const int t   = threadIdx.x;
    const int row = blockIdx.x * 32 + (t >> 4);
    const int cc  = t & 15;
    const size_t rbase = (size_t)row * 384;

    float t1 = 0.f, t2 = 0.f, t3 = 0.f;
#pragma unroll
    for (int j = 0; j < 4; ++j) {
        const int c = j * 16 + cc;
        float a1 = 0.f, a2 = 0.f, b2 = 0.f, a3 = 0.f, b3 = 0.f, c3 = 0.f;
#pragma unroll
        for (int qq = 0; qq < 4; ++qq) {
            const _Float16* p = part + (size_t)qq * 8192 * 384 + rbase;
            a1 += (float)p[c];
            a2 += (float)p[64 + c];
            b2 += (float)p[128 + c];
            a3 += (float)p[192 + c];
            b3 += (float)p[256 + c];
            c3 += (float)p[320 + c];
        }
        t1 += a1;
        t2 += a2 * b2;
        t3 += a3 * b3 * c3;
    }
#pragma unroll
    for (int off = 1; off < 16; off <<= 1) {
        t1 += __shfl_xor(t1, off, 16);
        t2 += __shfl_xor(t2, off, 16);
        t3 += __shfl_xor(t3, off, 16);
    }
    if (cc == 0) {
        const float s = sinws[row] + sinws[8192 + row]
                      + sinws[2 * 8192 + row] + sinws[3 * 8192 + row];
        out[row] = beta[0] + C[0] * t1 + C[1] * t2 + C[2] * t3 + Csin[0] * s;
    }
}

extern "C" void kernel_launch(void* const* d_in, const int* in_sizes, int n_in,
                              void* d_out, int out_size, void* d_ws, size_t ws_size,
                              hipStream_t stream) {
    const float* X   = (const float*)d_in[0];
    const float* U1  = (const float*)d_in[1];
    const float* U2  = (const float*)d_in[2];
    const float* U3  = (const float*)d_in[3];
    const float* Cc  = (const float*)d_in[4];
    const float* bet = (const float*)d_in[5];
    const float* Cs  = (const float*)d_in[6];
    float* out = (float*)d_out;

    unsigned short* W = (unsigned short*)d_ws;                  // 3 MiB, frag-packed
    float* sinws = (float*)((char*)d_ws + SINW_OFF);            // 128 KiB
    _Float16* part = (_Float16*)((char*)d_ws + PART_OFF);       // 24 MiB

    reg_init_kernel<<<1, 64, 0, stream>>>(Cc, Cs, out + 8192);
    build_w_kernel<<<128 * NT, 64, 0, stream>>>(U1, U2, U3, W, out + 8192);
    poly_main_kernel<<<1024, 256, 0, stream>>>(X, W, part, sinws);
    combine_kernel<<<256, 512, 0, stream>>>(part, sinws, Cc, bet, Cs, out);
}